// Round 8
// baseline (1351.072 us; speedup 1.0000x reference)
//
#include <hip/hip_runtime.h>
#include <math.h>

#define NL 28
#define DIM 1024
#define NHQ 16
#define NHKV 8
#define HDIM 128
#define NG 2
#define NFF 3072
#define NVOCAB 151936
#define NB 2
#define NPAST 1024
#define NPTOT 1025
#define EPSF 1e-6f
#define QKSCALE 0.08838834764831845f
#define LOGTHETA 13.815510557964274f

#define SQKV 4
#define SCH 16          // 16 chunks x 64 positions
#define NCOPY 256       // copy blocks appended to k1 (8 iters each)

// ws offsets (floats)
#define OFF_N1   0        // [NB][1024]: final nf (after kf_final)
#define OFF_H    2048     // [NB][1024] residual h entering current layer
#define OFF_H1   4096     // [NB][1024] h after attn residual
#define OFF_QKV  8192     // [4][NB][4096] qkv partials
#define OFF_AM   40960    // [NB*16][16] chunk max
#define OFF_AL   41472    // [NB*16][16] chunk sumexp
#define OFF_AO   41984    // [NB*16][16][128] chunk weighted-V
#define OFF_WO   107520   // [4][NB][1024] Wo partials
#define OFF_G    115712   // [4][NB][3072]
#define OFF_U    140288   // [4][NB][3072]
#define OFF_WD   164864   // [8][NB][1024]

#define PK_OFF ((size_t)NB*NVOCAB)
#define PV_OFF (PK_OFF + (size_t)NL*NB*NHKV*NPTOT*HDIM)
#define PK4 (PK_OFF/4)
#define PV4 (PV_OFF/4)

__device__ __forceinline__ float wave_red_sum(float v) {
  #pragma unroll
  for (int off = 32; off > 0; off >>= 1) v += __shfl_xor(v, off);
  return v;
}

// ---------------- K1: QKV GEMV partials (split=4) + past-KV copy blocks -------
// grid 256+NCOPY 1D, 256 threads
__global__ __launch_bounds__(256) void k1_qkv(
    const float* __restrict__ embeds,
    const float* __restrict__ Wq_, const float* __restrict__ Wk_,
    const float* __restrict__ Wv_, const float* __restrict__ ln1,
    const float* __restrict__ pastK, const float* __restrict__ pastV,
    float* __restrict__ out, float* __restrict__ ws, int l)
{
  int bid = blockIdx.x;
  int tid = threadIdx.x;
  if (bid >= 256) {
    // ---- dependency-free past-KV copy: pastK/V[l] -> out present region ----
    int cb = bid - 256;
    const float4* pk4 = (const float4*)pastK;
    const float4* pv4 = (const float4*)pastV;
    float4* o4 = (float4*)out;
    #pragma unroll
    for (int t = 0; t < 8; t++) {
      size_t idx = (size_t)(t*NCOPY + cb)*256 + tid;   // 0 .. 524287
      size_t pair = idx >> 15, j = idx & 32767;        // pair = b*8+kv
      size_t sbase = ((size_t)l*16 + pair)*32768 + j;  // NPAST*HDIM/4 = 32768
      size_t dbase = ((size_t)l*16 + pair)*32800 + j;  // NPTOT*HDIM/4 = 32800
      o4[PK4 + dbase] = pk4[sbase];
      o4[PV4 + dbase] = pv4[sbase];
    }
    return;
  }
  int bx = bid & 63, by = bid >> 6;   // by in 0..3 (256-row splits)
  int lane = tid & 63, w = tid >> 6;
  __shared__ __align__(16) float sh[NB][256];
  __shared__ __align__(16) float red[256*9];
  __shared__ float wr[8];

  int ct = tid & 15, rs = tid >> 4;   // 16 col-threads x 16 row-groups
  int colg = bx*64 + ct*4;
  const float* W; int O; int wcol;
  if (bx < 32)      { W = Wq_; O = 2048; wcol = colg; }
  else if (bx < 48) { W = Wk_; O = 1024; wcol = colg - 2048; }
  else              { W = Wv_; O = 1024; wcol = colg - 3072; }
  int r0 = rs*16;
  const float* Wp = W + (size_t)l*DIM*O + (size_t)(by*256 + r0)*O + wcol;
  float4 wb[16];

  {
    // (a) preamble loads
    int d = tid*4;
    float4 a0, a1, lw = *(const float4*)(ln1 + (size_t)l*DIM + d);
    if (l == 0) {
      a0 = *(const float4*)(embeds + d);
      a1 = *(const float4*)(embeds + DIM + d);
    } else {
      a0 = *(const float4*)(ws + OFF_H1 + d);
      a1 = *(const float4*)(ws + OFF_H1 + DIM + d);
      #pragma unroll
      for (int s = 0; s < 8; s++) {
        float4 p0 = *(const float4*)(ws + OFF_WD + (s*NB + 0)*DIM + d);
        float4 p1 = *(const float4*)(ws + OFF_WD + (s*NB + 1)*DIM + d);
        a0.x += p0.x; a0.y += p0.y; a0.z += p0.z; a0.w += p0.w;
        a1.x += p1.x; a1.y += p1.y; a1.z += p1.z; a1.w += p1.w;
      }
    }
    __builtin_amdgcn_sched_barrier(0);
    // (b) weight stream
    #pragma unroll
    for (int i = 0; i < 16; i++) wb[i] = *(const float4*)(Wp + (size_t)i*O);
    // (c) preamble compute (overlaps weight stream)
    if (bx == 0 && by == 0) {
      *(float4*)(ws + OFF_H + d) = a0;
      *(float4*)(ws + OFF_H + DIM + d) = a1;
    }
    float s0 = wave_red_sum(a0.x*a0.x + a0.y*a0.y + a0.z*a0.z + a0.w*a0.w);
    float s1 = wave_red_sum(a1.x*a1.x + a1.y*a1.y + a1.z*a1.z + a1.w*a1.w);
    if (lane == 0) { wr[w] = s0; wr[4+w] = s1; }
    __syncthreads();
    float rq0 = rsqrtf((wr[0]+wr[1]+wr[2]+wr[3])/DIM + EPSF);
    float rq1 = rsqrtf((wr[4]+wr[5]+wr[6]+wr[7])/DIM + EPSF);
    int r = d - by*256;
    if (r >= 0 && r < 256) {
      sh[0][r] = a0.x*rq0*lw.x; sh[0][r+1] = a0.y*rq0*lw.y;
      sh[0][r+2] = a0.z*rq0*lw.z; sh[0][r+3] = a0.w*rq0*lw.w;
      sh[1][r] = a1.x*rq1*lw.x; sh[1][r+1] = a1.y*rq1*lw.y;
      sh[1][r+2] = a1.z*rq1*lw.z; sh[1][r+3] = a1.w*rq1*lw.w;
    }
    __syncthreads();
  }

  float a[2][4] = {};
  #pragma unroll
  for (int i = 0; i < 16; i++) {
    float x0 = sh[0][r0+i], x1 = sh[1][r0+i];
    a[0][0] += x0*wb[i].x; a[0][1] += x0*wb[i].y; a[0][2] += x0*wb[i].z; a[0][3] += x0*wb[i].w;
    a[1][0] += x1*wb[i].x; a[1][1] += x1*wb[i].y; a[1][2] += x1*wb[i].z; a[1][3] += x1*wb[i].w;
  }
  float* rp = red + tid*9;
  #pragma unroll
  for (int e = 0; e < 4; e++) { rp[e] = a[0][e]; rp[4+e] = a[1][e]; }
  __syncthreads();
  if (tid < 16) {
    float o[8] = {};
    #pragma unroll
    for (int j = 0; j < 16; j++) {
      const float* q = red + (size_t)(j*16 + tid)*9;
      #pragma unroll
      for (int e = 0; e < 8; e++) o[e] += q[e];
    }
    int cg = bx*64 + tid*4;
    #pragma unroll
    for (int e = 0; e < 4; e++) {
      ws[OFF_QKV + (by*NB + 0)*4096 + cg + e] = o[e];
      ws[OFF_QKV + (by*NB + 1)*4096 + cg + e] = o[4+e];
    }
  }
}

// ---------------- K2: qkv finalize + qknorm + rope + attention ----------------
// grid (16 chunks, NHKV, NB), 256 threads; 64 positions/chunk
__global__ __launch_bounds__(256) void k2_attn(
    const float* __restrict__ pastK, const float* __restrict__ pastV,
    const int* __restrict__ posids, const float* __restrict__ qnw,
    const float* __restrict__ knw, float* __restrict__ out,
    float* __restrict__ ws, int l)
{
  int c = blockIdx.x, kv = blockIdx.y, b = blockIdx.z;
  int tid = threadIdx.x;
  int lane = tid & 63, w = tid >> 6;
  int g = tid >> 7, o = tid & 127;
  __shared__ __align__(16) float qf[NG][HDIM];
  __shared__ __align__(16) float kf[HDIM];
  __shared__ __align__(16) float vf[HDIM];
  __shared__ __align__(16) float pre[NG][HDIM];
  __shared__ __align__(16) float kpre[HDIM];
  __shared__ __align__(16) float po[8][NG][HDIM];
  __shared__ float wr[8];
  __shared__ float pm[8][NG], pl[8][NG];

  // (a) preamble loads: qkv partials (4 splits) + norm weights + pos
  int hq = kv*NG + g;
  float qp = 0.f, kp = 0.f;
  #pragma unroll
  for (int s = 0; s < SQKV; s++) qp += ws[OFF_QKV + (s*NB + b)*4096 + hq*HDIM + o];
  int kvslot = g ? 3072 : 2048;
  #pragma unroll
  for (int s = 0; s < SQKV; s++) kp += ws[OFF_QKV + (s*NB + b)*4096 + kvslot + kv*HDIM + o];
  float qw_ = qnw[l*HDIM + o];
  float kw_ = knw[l*HDIM + o];
  float pos = (float)posids[b];
  __builtin_amdgcn_sched_barrier(0);

  // (b) KV prefetch: 8 positions per 32-lane group (static trip count)
  int grp = tid >> 5, q = tid & 31;
  int p0 = c*64;
  size_t pastb4 = ((((size_t)l*NB + b)*NHKV + kv)*NPAST)*(HDIM/4);
  size_t presbase = ((((size_t)l*NB + b)*NHKV + kv)*NPTOT)*HDIM;
  const float4* pk4 = (const float4*)pastK;
  const float4* pv4 = (const float4*)pastV;
  float4 kk[8], vv[8];
  #pragma unroll
  for (int i = 0; i < 8; i++) {
    size_t p = p0 + grp + i*8;
    kk[i] = pk4[pastb4 + p*(HDIM/4) + q];
    vv[i] = pv4[pastb4 + p*(HDIM/4) + q];
  }
  __builtin_amdgcn_sched_barrier(0);

  // (c) preamble compute: qknorm + rope (overlaps KV stream)
  float sq = wave_red_sum(qp*qp);
  float sk = wave_red_sum(kp*kp);
  if (lane == 0) { wr[w] = sq; wr[4+w] = sk; }
  __syncthreads();
  float qr = rsqrtf((wr[g<<1] + wr[(g<<1)+1])/HDIM + EPSF);
  float kr = rsqrtf((wr[4] + wr[5])/HDIM + EPSF);
  float qn = qp*qr*qw_;
  pre[g][o] = qn;
  if (g == 0) kpre[o] = kp*kr*kw_;
  else vf[o] = kp;
  __syncthreads();
  float ang = pos * expf(-(2.0f*(float)(o & 63)/(float)HDIM)*LOGTHETA);
  float sn, cs;
  sincosf(ang, &sn, &cs);
  {
    float rotq = (o < 64) ? -pre[g][o+64] : pre[g][o-64];
    qf[g][o] = qn*cs + rotq*sn;
    if (g == 0) {
      float kx = kpre[o];
      float rotk = (o < 64) ? -kpre[o+64] : kpre[o-64];
      kf[o] = kx*cs + rotk*sn;
    }
  }
  __syncthreads();

  // (d) scores (static) + optional new-token term on the last chunk
  float4 q0 = *(const float4*)&qf[0][q*4];
  float4 q1 = *(const float4*)&qf[1][q*4];
  float sc0[8], sc1[8];
  #pragma unroll
  for (int i = 0; i < 8; i++) {
    float d0 = q0.x*kk[i].x + q0.y*kk[i].y + q0.z*kk[i].z + q0.w*kk[i].w;
    float d1 = q1.x*kk[i].x + q1.y*kk[i].y + q1.z*kk[i].z + q1.w*kk[i].w;
    #pragma unroll
    for (int off = 16; off > 0; off >>= 1) {
      d0 += __shfl_xor(d0, off);
      d1 += __shfl_xor(d1, off);
    }
    sc0[i] = d0*QKSCALE; sc1[i] = d1*QKSCALE;
  }
  float xs0 = -1e30f, xs1 = -1e30f;
  float4 xv = make_float4(0.f, 0.f, 0.f, 0.f);
  if (c == SCH-1 && grp == 0) {
    float4 kX = *(const float4*)&kf[q*4];
    xv = *(const float4*)&vf[q*4];
    *(float4*)(out + PK_OFF + presbase + (size_t)NPAST*HDIM + q*4) = kX;
    *(float4*)(out + PV_OFF + presbase + (size_t)NPAST*HDIM + q*4) = xv;
    float d0 = q0.x*kX.x + q0.y*kX.y + q0.z*kX.z + q0.w*kX.w;
    float d1 = q1.x*kX.x + q1.y*kX.y + q1.z*kX.z + q1.w*kX.w;
    #pragma unroll
    for (int off = 16; off > 0; off >>= 1) {
      d0 += __shfl_xor(d0, off);
      d1 += __shfl_xor(d1, off);
    }
    xs0 = d0*QKSCALE; xs1 = d1*QKSCALE;
  }
  float m0 = sc0[0], m1 = sc1[0];
  #pragma unroll
  for (int i = 1; i < 8; i++) { m0 = fmaxf(m0, sc0[i]); m1 = fmaxf(m1, sc1[i]); }
  m0 = fmaxf(m0, xs0); m1 = fmaxf(m1, xs1);
  if (q == 0) { pm[grp][0] = m0; pm[grp][1] = m1; }
  __syncthreads();
  float M0 = -1e30f, M1 = -1e30f;
  #pragma unroll
  for (int j = 0; j < 8; j++) { M0 = fmaxf(M0, pm[j][0]); M1 = fmaxf(M1, pm[j][1]); }
  float l0 = 0.f, l1 = 0.f;
  float4 o0 = {0,0,0,0}, o1 = {0,0,0,0};
  #pragma unroll
  for (int j = 0; j < 8; j++) {
    float w0 = __expf(sc0[j] - M0), w1 = __expf(sc1[j] - M1);
    l0 += w0; l1 += w1;
    o0.x += w0*vv[j].x; o0.y += w0*vv[j].y; o0.z += w0*vv[j].z; o0.w += w0*vv[j].w;
    o1.x += w1*vv[j].x; o1.y += w1*vv[j].y; o1.z += w1*vv[j].z; o1.w += w1*vv[j].w;
  }
  { // new-token term: exp(-1e30 - M) == 0 folds it out elsewhere
    float w0 = __expf(xs0 - M0), w1 = __expf(xs1 - M1);
    l0 += w0; l1 += w1;
    o0.x += w0*xv.x; o0.y += w0*xv.y; o0.z += w0*xv.z; o0.w += w0*xv.w;
    o1.x += w1*xv.x; o1.y += w1*xv.y; o1.z += w1*xv.z; o1.w += w1*xv.w;
  }
  if (q == 0) { pl[grp][0] = l0; pl[grp][1] = l1; }
  *(float4*)&po[grp][0][q*4] = o0;
  *(float4*)&po[grp][1][q*4] = o1;
  __syncthreads();
  {
    int head = tid >> 7, dd = tid & 127;
    float acc = 0.f;
    #pragma unroll
    for (int j = 0; j < 8; j++) acc += po[j][head][dd];
    int base = ((b*NHKV + kv)*NG + head)*SCH + c;
    ws[OFF_AO + (size_t)base*HDIM + dd] = acc;
    if (dd == 0) {
      float ll = 0.f;
      #pragma unroll
      for (int j = 0; j < 8; j++) ll += pl[j][head];
      ws[OFF_AM + base] = (head ? M1 : M0);
      ws[OFF_AL + base] = ll;
    }
  }
}

// ---------------- K3: softmax combine + Wo GEMV partials (split=4) ------------
// grid (64 colTiles(16), 4 headQuads(512 rows)), 256 threads
__global__ __launch_bounds__(256) void k3_wo(const float* __restrict__ Wo_,
    float* __restrict__ ws, int l)
{
  int bx = blockIdx.x, by = blockIdx.y;
  int tid = threadIdx.x;
  __shared__ __align__(16) float x[NB][512];
  __shared__ float wf[NB][4][SCH];
  __shared__ float invL[NB][4];
  __shared__ __align__(16) float red[256*9];

  // (a) m/l finalize: 128 threads, one 16-lane group per (b,hh)
  if (tid < 128) {
    int b = tid >> 6, hh = (tid >> 4) & 3, cc = tid & 15;
    int hb = b*16 + by*4 + hh;
    float m  = ws[OFF_AM + hb*SCH + cc];
    float ll = ws[OFF_AL + hb*SCH + cc];
    float M = m;
    #pragma unroll
    for (int off = 8; off > 0; off >>= 1) M = fmaxf(M, __shfl_xor(M, off));
    float f = __expf(m - M);
    float Ls = ll*f;
    #pragma unroll
    for (int off = 8; off > 0; off >>= 1) Ls += __shfl_xor(Ls, off);
    wf[b][hh][cc] = f;
    if (cc == 0) invL[b][hh] = 1.0f/Ls;
  }
  __builtin_amdgcn_sched_barrier(0);

  // (b) weight stream
  int ct = tid & 3, rs = tid >> 2;      // 4 col-threads x 64 row-groups
  int col = bx*16 + ct*4;
  int r0 = rs*8;
  const float* Wp = Wo_ + (size_t)l*(NHQ*HDIM)*DIM + (size_t)(by*512 + r0)*DIM + col;
  float4 wb[8];
  #pragma unroll
  for (int i = 0; i < 8; i++) wb[i] = *(const float4*)(Wp + (size_t)i*DIM);
  __syncthreads();

  // (c) x combine (overlaps weight stream)
  for (int e = tid; e < 1024; e += 256) {
    int b = e >> 9, rr = e & 511, hh = rr >> 7, dd = rr & 127;
    int hb = b*16 + by*4 + hh;
    const float* op = ws + OFF_AO + (size_t)(hb*SCH)*HDIM + dd;
    float acc = 0.f;
    #pragma unroll
    for (int cc = 0; cc < SCH; cc++) acc += op[(size_t)cc*HDIM]*wf[b][hh][cc];
    x[b][rr] = acc*invL[b][hh];
  }
  __syncthreads();
  float a[2][4] = {};
  #pragma unroll
  for (int i = 0; i < 8; i++) {
    float x0 = x[0][r0+i], x1 = x[1][r0+i];
    a[0][0] += x0*wb[i].x; a[0][1] += x0*wb[i].y; a[0][2] += x0*wb[i].z; a[0][3] += x0*wb[i].w;
    a[1][0] += x1*wb[i].x; a[1][1] += x1*wb[i].y; a[1][2] += x1*wb[i].z; a[1][3] += x1*wb[i].w;
  }
  float* rp = red + tid*9;
  #pragma unroll
  for (int e = 0; e < 4; e++) { rp[e] = a[0][e]; rp[4+e] = a[1][e]; }
  __syncthreads();
  if (tid < 4) {
    float o[8] = {};
    #pragma unroll
    for (int j = 0; j < 64; j++) {
      const float* qq = red + (size_t)(j*4 + tid)*9;
      #pragma unroll
      for (int e = 0; e < 8; e++) o[e] += qq[e];
    }
    int cg = bx*16 + tid*4;
    #pragma unroll
    for (int e = 0; e < 4; e++) {
      ws[OFF_WO + (by*NB + 0)*DIM + cg + e] = o[e];
      ws[OFF_WO + (by*NB + 1)*DIM + cg + e] = o[4+e];
    }
  }
}

// ---------------- K4: h1+n2 recompute + Wg/Wu GEMV partials (split=4) ---------
// grid (96 colTiles(32), 4 rowSplits(256)), 256 threads
__global__ __launch_bounds__(256) void k4_mlp1(const float* __restrict__ Wg_,
    const float* __restrict__ Wu_, const float* __restrict__ ln2,
    float* __restrict__ ws, int l)
{
  int bx = blockIdx.x, by = blockIdx.y;
  int tid = threadIdx.x;
  int lane = tid & 63, w = tid >> 6;
  __shared__ __align__(16) float sh[NB][256];
  __shared__ __align__(16) float redG[256*9];
  __shared__ __align__(16) float redU[256*9];
  __shared__ float wr[8];

  // (a) preamble loads: h + WO partials (4 splits)
  int d = tid*4;
  float4 a0 = *(const float4*)(ws + OFF_H + d);
  float4 a1 = *(const float4*)(ws + OFF_H + DIM + d);
  #pragma unroll
  for (int s = 0; s < 4; s++) {
    float4 p0 = *(const float4*)(ws + OFF_WO + (s*NB + 0)*DIM + d);
    float4 p1 = *(const float4*)(ws + OFF_WO + (s*NB + 1)*DIM + d);
    a0.x += p0.x; a0.y += p0.y; a0.z += p0.z; a0.w += p0.w;
    a1.x += p1.x; a1.y += p1.y; a1.z += p1.z; a1.w += p1.w;
  }
  float4 lw = *(const float4*)(ln2 + (size_t)l*DIM + d);
  __builtin_amdgcn_sched_barrier(0);

  // (b) weight stream
  int ct = tid & 7, rs = tid >> 3;    // 8 col-threads x 32 row-groups
  int col = bx*32 + ct*4;
  int r0 = rs*8;
  const float* Wgp = Wg_ + (size_t)l*DIM*NFF + (size_t)(by*256 + r0)*NFF + col;
  const float* Wup = Wu_ + (size_t)l*DIM*NFF + (size_t)(by*256 + r0)*NFF + col;
  float4 wg[8], wu[8];
  #pragma unroll
  for (int i = 0; i < 8; i++) {
    wg[i] = *(const float4*)(Wgp + (size_t)i*NFF);
    wu[i] = *(const float4*)(Wup + (size_t)i*NFF);
  }

  // (c) preamble compute
  if (bx == 0 && by == 0) {
    *(float4*)(ws + OFF_H1 + d) = a0;
    *(float4*)(ws + OFF_H1 + DIM + d) = a1;
  }
  float s0 = wave_red_sum(a0.x*a0.x + a0.y*a0.y + a0.z*a0.z + a0.w*a0.w);
  float s1 = wave_red_sum(a1.x*a1.x + a1.y*a1.y + a1.z*a1.z + a1.w*a1.w);
  if (lane == 0) { wr[w] = s0; wr[4+w] = s1; }
  __syncthreads();
  float rq0 = rsqrtf((wr[0]+wr[1]+wr[2]+wr[3])/DIM + EPSF);
  float rq1 = rsqrtf((wr[4]+wr[5]+wr[6]+wr[7])/DIM + EPSF);
  int r = d - by*256;
  if (r >= 0 && r < 256) {
    sh[0][r] = a0.x*rq0*lw.x; sh[0][r+1] = a0.y*rq0*lw.y;
    sh[0][r+2] = a0.z*rq0*lw.z; sh[0][r+3] = a0.w*rq0*lw.w;
    sh[1][r] = a1.x*rq1*lw.x; sh[1][r+1] = a1.y*rq1*lw.y;
    sh[1][r+2] = a1.z*rq1*lw.z; sh[1][r+3] = a1.w*rq1*lw.w;
  }
  __syncthreads();

  float ag[2][4] = {}, au[2][4] = {};
  #pragma unroll
  for (int i = 0; i < 8; i++) {
    float x0 = sh[0][r0+i], x1 = sh[1][r0+i];
    ag[0][0] += x0*wg[i].x; ag[0][1] += x0*wg[i].y; ag[0][2] += x0*wg[i].z; ag[0][3] += x0*wg[i].w;
    ag[1][0] += x1*wg[i].x; ag[1][1] += x1*wg[i].y; ag[1][2] += x1*wg[i].z; ag[1][3] += x1*wg[i].w;
    au[0][0] += x0*wu[i].x; au[0][1] += x0*wu[i].y; au[0][2] += x0*wu[i].z; au[0][3] += x0*wu[i].w;
    au[1][0] += x1*wu[i].x; au[1][1] += x1*wu[i].y; au[1][2] += x1*wu[i].z; au[1][3] += x1*wu[i].w;
  }
  float* rpG = redG + tid*9;
  float* rpU = redU + tid*9;
  #pragma unroll
  for (int e = 0; e < 4; e++) {
    rpG[e] = ag[0][e]; rpG[4+e] = ag[1][e];
    rpU[e] = au[0][e]; rpU[4+e] = au[1][e];
  }
  __syncthreads();
  if (tid < 8) {              // wave 0 reduces G
    float o[8] = {};
    #pragma unroll
    for (int j = 0; j < 32; j++) {
      const float* qq = redG + (size_t)(j*8 + tid)*9;
      #pragma unroll
      for (int e = 0; e < 8; e++) o[e] += qq[e];
    }
    int cg = bx*32 + tid*4;
    #pragma unroll
    for (int e = 0; e < 4; e++) {
      ws[OFF_G + (by*NB + 0)*NFF + cg + e] = o[e];
      ws[OFF_G + (by*NB + 1)*NFF + cg + e] = o[4+e];
    }
  } else if (tid >= 64 && tid < 72) {   // wave 1 reduces U concurrently
    int t = tid - 64;
    float o[8] = {};
    #pragma unroll
    for (int j = 0; j < 32; j++) {
      const float* qq = redU + (size_t)(j*8 + t)*9;
      #pragma unroll
      for (int e = 0; e < 8; e++) o[e] += qq[e];
    }
    int cg = bx*32 + t*4;
    #pragma unroll
    for (int e = 0; e < 4; e++) {
      ws[OFF_U + (by*NB + 0)*NFF + cg + e] = o[e];
      ws[OFF_U + (by*NB + 1)*NFF + cg + e] = o[4+e];
    }
  }
}

// ---------------- K5: swiglu slice + Wd GEMV partials -------------------------
// grid (32 colTiles(32), 8 ffSplits(384)), 256 threads
__global__ __launch_bounds__(256) void k5_mlp2(const float* __restrict__ Wd_,
    float* __restrict__ ws, int l)
{
  int bx = blockIdx.x, by = blockIdx.y;
  int tid = threadIdx.x;
  __shared__ __align__(16) float act[NB][384];
  __shared__ __align__(16) float red[256*9];

  // (a) preamble loads: G/U partials (4 splits), 192 active threads
  float4 gacc = {0,0,0,0}, uacc = {0,0,0,0};
  int pb = 0, pf4 = 0;
  if (tid < 192) {
    pb = tid / 96; pf4 = tid % 96;
    int f4 = (by*384)/4 + pf4;
    const float4* Gp = (const float4*)(ws + OFF_G);
    const float4* Up = (const float4*)(ws + OFF_U);
    #pragma unroll
    for (int s = 0; s < 4; s++) {
      float4 g4 = Gp[(size_t)(s*NB + pb)*(NFF/4) + f4];
      float4 u4 = Up[(size_t)(s*NB + pb)*(NFF/4) + f4];
      gacc.x += g4.x; gacc.y += g4.y; gacc.z += g4.z; gacc.w += g4.w;
      uacc.x += u4.x; uacc.y += u4.y; uacc.z += u4.z; uacc.w += u4.w;
    }
  }
  __builtin_amdgcn_sched_barrier(0);

  // (b) weight stream
  int ct = tid & 7, rs = tid >> 3;
  int col = bx*32 + ct*4;
  int r0 = rs*12;
  const float* Wp = Wd_ + (size_t)l*NFF*DIM + (size_t)(by*384 + r0)*DIM + col;
  float4 wb[12];
  #pragma unroll
  for (int i = 0; i < 12; i++) wb[i] = *(const float4*)(Wp + (size_t)i*DIM);

  // (c) swiglu + LDS store
  if (tid < 192) {
    float4 r;
    r.x = (gacc.x / (1.0f + __expf(-gacc.x)))*uacc.x;
    r.y = (gacc.y / (1.0f + __expf(-gacc.y)))*uacc.y;
    r.z = (gacc.z / (1.0f + __expf(-gacc.z)))*uacc.z;
    r.w = (gacc.w / (1.0f + __expf(-gacc.w)))*uacc.w;
    *(float4*)&act[pb][pf4*4] = r;
  }
  __syncthreads();

  float a[2][4] = {};
  #pragma unroll
  for (int i = 0; i < 12; i++) {
    float x0 = act[0][r0+i], x1 = act[1][r0+i];
    a[0][0] += x0*wb[i].x; a[0][1] += x0*wb[i].y; a[0][2] += x0*wb[i].z; a[0][3] += x0*wb[i].w;
    a[1][0] += x1*wb[i].x; a[1][1] += x1*wb[i].y; a[1][2] += x1*wb[i].z; a[1][3] += x1*wb[i].w;
  }
  float* rp = red + tid*9;
  #pragma unroll
  for (int e = 0; e < 4; e++) { rp[e] = a[0][e]; rp[4+e] = a[1][e]; }
  __syncthreads();
  if (tid < 8) {
    float o[8] = {};
    #pragma unroll
    for (int j = 0; j < 32; j++) {
      const float* qq = red + (size_t)(j*8 + tid)*9;
      #pragma unroll
      for (int e = 0; e < 8; e++) o[e] += qq[e];
    }
    int cg = bx*32 + tid*4;
    #pragma unroll
    for (int e = 0; e < 4; e++) {
      ws[OFF_WD + (by*NB + 0)*DIM + cg + e] = o[e];
      ws[OFF_WD + (by*NB + 1)*DIM + cg + e] = o[4+e];
    }
  }
}

// ---------------- KF: finalize h2 + final rmsnorm -> nf (1 block) -------------
__global__ __launch_bounds__(256) void kf_final(const float* __restrict__ fnw,
    float* __restrict__ ws)
{
  int tid = threadIdx.x;
  int lane = tid & 63, w = tid >> 6;
  __shared__ float wr[8];
  int d = tid*4;
  float4 a0 = *(const float4*)(ws + OFF_H1 + d);
  float4 a1 = *(const float4*)(ws + OFF_H1 + DIM + d);
  #pragma unroll
  for (int s = 0; s < 8; s++) {
    float4 p0 = *(const float4*)(ws + OFF_WD + (s*NB + 0)*DIM + d);
    float4 p1 = *(const float4*)(ws + OFF_WD + (s*NB + 1)*DIM + d);
    a0.x += p0.x; a0.y += p0.y; a0.z += p0.z; a0.w += p0.w;
    a1.x += p1.x; a1.y += p1.y; a1.z += p1.z; a1.w += p1.w;
  }
  float4 fw = *(const float4*)(fnw + d);
  float s0 = wave_red_sum(a0.x*a0.x + a0.y*a0.y + a0.z*a0.z + a0.w*a0.w);
  float s1 = wave_red_sum(a1.x*a1.x + a1.y*a1.y + a1.z*a1.z + a1.w*a1.w);
  if (lane == 0) { wr[w] = s0; wr[4+w] = s1; }
  __syncthreads();
  float rq0 = rsqrtf((wr[0]+wr[1]+wr[2]+wr[3])/DIM + EPSF);
  float rq1 = rsqrtf((wr[4]+wr[5]+wr[6]+wr[7])/DIM + EPSF);
  float4 n0 = make_float4(a0.x*rq0*fw.x, a0.y*rq0*fw.y, a0.z*rq0*fw.z, a0.w*rq0*fw.w);
  float4 n1 = make_float4(a1.x*rq1*fw.x, a1.y*rq1*fw.y, a1.z*rq1*fw.z, a1.w*rq1*fw.w);
  *(float4*)(ws + OFF_N1 + d) = n0;
  *(float4*)(ws + OFF_N1 + DIM + d) = n1;
}

// ---------------- K6: lm_head GEMV (nf precomputed) ---------------------------
// grid 2374 blocks (64 cols each), 256 threads
__global__ __launch_bounds__(256) void k6_lmhead(const float* __restrict__ lmw,
    const float* __restrict__ ws, float* __restrict__ out)
{
  __shared__ __align__(16) float nf[NB*DIM];
  __shared__ __align__(16) float red[256*9];
  int tid = threadIdx.x;
  *(float4*)&nf[tid*4]        = *(const float4*)(ws + OFF_N1 + tid*4);
  *(float4*)&nf[1024 + tid*4] = *(const float4*)(ws + OFF_N1 + 1024 + tid*4);
  __syncthreads();

  int ct = tid & 15, rs = tid >> 4;
  int col = blockIdx.x*64 + ct*4;
  const float* Wp = lmw + (size_t)(rs*64)*NVOCAB + col;
  float a[2][4] = {};
  for (int t = 0; t < 8; t++) {
    float4 wb[8];
    #pragma unroll
    for (int i = 0; i < 8; i++)
      wb[i] = *(const float4*)(Wp + (size_t)(t*8 + i)*NVOCAB);
    #pragma unroll
    for (int i = 0; i < 8; i++) {
      int rr = rs*64 + t*8 + i;
      float x0 = nf[rr], x1 = nf[DIM+rr];
      a[0][0] += x0*wb[i].x; a[0][1] += x0*wb[i].y; a[0][2] += x0*wb[i].z; a[0][3] += x0*wb[i].w;
      a[1][0] += x1*wb[i].x; a[1][1] += x1*wb[i].y; a[1][2] += x1*wb[i].z; a[1][3] += x1*wb[i].w;
    }
  }
  float* rp = red + tid*9;
  #pragma unroll
  for (int e = 0; e < 4; e++) { rp[e] = a[0][e]; rp[4+e] = a[1][e]; }
  __syncthreads();
  if (tid < 16) {
    float o[8] = {};
    #pragma unroll
    for (int j = 0; j < 16; j++) {
      const float* qq = red + (size_t)(j*16 + tid)*9;
      #pragma unroll
      for (int e = 0; e < 8; e++) o[e] += qq[e];
    }
    int cg = blockIdx.x*64 + tid*4;
    #pragma unroll
    for (int e = 0; e < 4; e++) {
      out[cg + e] = o[e];
      out[NVOCAB + cg + e] = o[4+e];
    }
  }
}

extern "C" void kernel_launch(void* const* d_in, const int* in_sizes, int n_in,
                              void* d_out, int out_size, void* d_ws, size_t ws_size,
                              hipStream_t stream) {
  (void)in_sizes; (void)n_in; (void)out_size; (void)ws_size;
  const float* embeds = (const float*)d_in[0];
  const int*   posids = (const int*)d_in[1];
  const float* pastK  = (const float*)d_in[2];
  const float* pastV  = (const float*)d_in[3];
  const float* Wq     = (const float*)d_in[4];
  const float* Wk     = (const float*)d_in[5];
  const float* Wv     = (const float*)d_in[6];
  const float* Wo     = (const float*)d_in[7];
  const float* Wg     = (const float*)d_in[8];
  const float* Wu     = (const float*)d_in[9];
  const float* Wd     = (const float*)d_in[10];
  const float* ln1    = (const float*)d_in[11];
  const float* ln2    = (const float*)d_in[12];
  const float* qnw    = (const float*)d_in[13];
  const float* knw    = (const float*)d_in[14];
  const float* fnw    = (const float*)d_in[15];
  const float* lmw    = (const float*)d_in[16];
  float* out = (float*)d_out;
  float* ws  = (float*)d_ws;

  for (int l = 0; l < NL; l++) {
    k1_qkv <<<256 + NCOPY, 256, 0, stream>>>(embeds, Wq, Wk, Wv, ln1, pastK, pastV, out, ws, l);
    k2_attn<<<dim3(SCH, NHKV, NB), 256, 0, stream>>>(pastK, pastV, posids, qnw, knw, out, ws, l);
    k3_wo  <<<dim3(64, 4), 256, 0, stream>>>(Wo, ws, l);
    k4_mlp1<<<dim3(96, 4), 256, 0, stream>>>(Wg, Wu, ln2, ws, l);
    k5_mlp2<<<dim3(32, 8), 256, 0, stream>>>(Wd, ws, l);
  }
  kf_final<<<1, 256, 0, stream>>>(fnw, ws);
  k6_lmhead<<<NVOCAB/64, 256, 0, stream>>>(lmw, ws, out);
}

// Round 9
// 1279.137 us; speedup vs baseline: 1.0562x; 1.0562x over previous
//
#include <hip/hip_runtime.h>
#include <math.h>

#define NL 28
#define DIM 1024
#define NHQ 16
#define NHKV 8
#define HDIM 128
#define NG 2
#define NFF 3072
#define NVOCAB 151936
#define NB 2
#define NPAST 1024
#define NPTOT 1025
#define EPSF 1e-6f
#define QKSCALE 0.08838834764831845f
#define LOGTHETA 13.815510557964274f

#define SQKV 4
#define SCH 16          // 16 chunks x 64 positions

// ws offsets (floats)
#define OFF_N1   0        // [NB][1024]: final nf (after kf_final)
#define OFF_H    2048     // [NB][1024] residual h entering current layer
#define OFF_H1   4096     // [NB][1024] h after attn residual
#define OFF_QKV  8192     // [4][NB][4096] qkv partials
#define OFF_AM   40960    // [NB*16][16] chunk max
#define OFF_AL   41472    // [NB*16][16] chunk sumexp
#define OFF_AO   41984    // [NB*16][16][128] chunk weighted-V
#define OFF_WO   107520   // [4][NB][1024] Wo partials
#define OFF_G    115712   // [4][NB][3072]
#define OFF_U    140288   // [4][NB][3072]
#define OFF_WD   164864   // [8][NB][1024]

#define PK_OFF ((size_t)NB*NVOCAB)
#define PV_OFF (PK_OFF + (size_t)NL*NB*NHKV*NPTOT*HDIM)

__device__ __forceinline__ float wave_red_sum(float v) {
  #pragma unroll
  for (int off = 32; off > 0; off >>= 1) v += __shfl_xor(v, off);
  return v;
}

// ---------------- K1: QKV GEMV partials (split=4) ------------------------------
// grid 256 1D, 256 threads
__global__ __launch_bounds__(256) void k1_qkv(
    const float* __restrict__ embeds,
    const float* __restrict__ Wq_, const float* __restrict__ Wk_,
    const float* __restrict__ Wv_, const float* __restrict__ ln1,
    float* __restrict__ ws, int l)
{
  int bid = blockIdx.x;
  int tid = threadIdx.x;
  int bx = bid & 63, by = bid >> 6;   // by in 0..3 (256-row splits)
  int lane = tid & 63, w = tid >> 6;
  __shared__ __align__(16) float sh[NB][256];
  __shared__ __align__(16) float red[256*9];
  __shared__ float wr[8];

  int ct = tid & 15, rs = tid >> 4;   // 16 col-threads x 16 row-groups
  int colg = bx*64 + ct*4;
  const float* W; int O; int wcol;
  if (bx < 32)      { W = Wq_; O = 2048; wcol = colg; }
  else if (bx < 48) { W = Wk_; O = 1024; wcol = colg - 2048; }
  else              { W = Wv_; O = 1024; wcol = colg - 3072; }
  int r0 = rs*16;
  const float* Wp = W + (size_t)l*DIM*O + (size_t)(by*256 + r0)*O + wcol;
  float4 wb[16];

  {
    // (a) preamble loads
    int d = tid*4;
    float4 a0, a1, lw = *(const float4*)(ln1 + (size_t)l*DIM + d);
    if (l == 0) {
      a0 = *(const float4*)(embeds + d);
      a1 = *(const float4*)(embeds + DIM + d);
    } else {
      a0 = *(const float4*)(ws + OFF_H1 + d);
      a1 = *(const float4*)(ws + OFF_H1 + DIM + d);
      #pragma unroll
      for (int s = 0; s < 8; s++) {
        float4 p0 = *(const float4*)(ws + OFF_WD + (s*NB + 0)*DIM + d);
        float4 p1 = *(const float4*)(ws + OFF_WD + (s*NB + 1)*DIM + d);
        a0.x += p0.x; a0.y += p0.y; a0.z += p0.z; a0.w += p0.w;
        a1.x += p1.x; a1.y += p1.y; a1.z += p1.z; a1.w += p1.w;
      }
    }
    __builtin_amdgcn_sched_barrier(0);
    // (b) weight stream
    #pragma unroll
    for (int i = 0; i < 16; i++) wb[i] = *(const float4*)(Wp + (size_t)i*O);
    // (c) preamble compute (overlaps weight stream)
    if (bx == 0 && by == 0) {
      *(float4*)(ws + OFF_H + d) = a0;
      *(float4*)(ws + OFF_H + DIM + d) = a1;
    }
    float s0 = wave_red_sum(a0.x*a0.x + a0.y*a0.y + a0.z*a0.z + a0.w*a0.w);
    float s1 = wave_red_sum(a1.x*a1.x + a1.y*a1.y + a1.z*a1.z + a1.w*a1.w);
    if (lane == 0) { wr[w] = s0; wr[4+w] = s1; }
    __syncthreads();
    float rq0 = rsqrtf((wr[0]+wr[1]+wr[2]+wr[3])/DIM + EPSF);
    float rq1 = rsqrtf((wr[4]+wr[5]+wr[6]+wr[7])/DIM + EPSF);
    int r = d - by*256;
    if (r >= 0 && r < 256) {
      sh[0][r] = a0.x*rq0*lw.x; sh[0][r+1] = a0.y*rq0*lw.y;
      sh[0][r+2] = a0.z*rq0*lw.z; sh[0][r+3] = a0.w*rq0*lw.w;
      sh[1][r] = a1.x*rq1*lw.x; sh[1][r+1] = a1.y*rq1*lw.y;
      sh[1][r+2] = a1.z*rq1*lw.z; sh[1][r+3] = a1.w*rq1*lw.w;
    }
    __syncthreads();
  }

  float a[2][4] = {};
  #pragma unroll
  for (int i = 0; i < 16; i++) {
    float x0 = sh[0][r0+i], x1 = sh[1][r0+i];
    a[0][0] += x0*wb[i].x; a[0][1] += x0*wb[i].y; a[0][2] += x0*wb[i].z; a[0][3] += x0*wb[i].w;
    a[1][0] += x1*wb[i].x; a[1][1] += x1*wb[i].y; a[1][2] += x1*wb[i].z; a[1][3] += x1*wb[i].w;
  }
  float* rp = red + tid*9;
  #pragma unroll
  for (int e = 0; e < 4; e++) { rp[e] = a[0][e]; rp[4+e] = a[1][e]; }
  __syncthreads();
  if (tid < 16) {
    float o[8] = {};
    #pragma unroll
    for (int j = 0; j < 16; j++) {
      const float* q = red + (size_t)(j*16 + tid)*9;
      #pragma unroll
      for (int e = 0; e < 8; e++) o[e] += q[e];
    }
    int cg = bx*64 + tid*4;
    #pragma unroll
    for (int e = 0; e < 4; e++) {
      ws[OFF_QKV + (by*NB + 0)*4096 + cg + e] = o[e];
      ws[OFF_QKV + (by*NB + 1)*4096 + cg + e] = o[4+e];
    }
  }
}

// ---------------- K2: qkv finalize + qknorm + rope + KV append + attention -----
// grid (16 chunks, NHKV, NB), 256 threads; 64 positions/chunk
__global__ __launch_bounds__(256) void k2_attn(
    const float* __restrict__ pastK, const float* __restrict__ pastV,
    const int* __restrict__ posids, const float* __restrict__ qnw,
    const float* __restrict__ knw, float* __restrict__ out,
    float* __restrict__ ws, int l)
{
  int c = blockIdx.x, kv = blockIdx.y, b = blockIdx.z;
  int tid = threadIdx.x;
  int lane = tid & 63, w = tid >> 6;
  int g = tid >> 7, o = tid & 127;
  __shared__ __align__(16) float qf[NG][HDIM];
  __shared__ __align__(16) float kf[HDIM];
  __shared__ __align__(16) float vf[HDIM];
  __shared__ __align__(16) float pre[NG][HDIM];
  __shared__ __align__(16) float kpre[HDIM];
  __shared__ __align__(16) float po[8][NG][HDIM];
  __shared__ float wr[8];
  __shared__ float pm[8][NG], pl[8][NG];

  // (a) preamble loads: qkv partials (4 splits) + norm weights + pos
  int hq = kv*NG + g;
  float qp = 0.f, kp = 0.f;
  #pragma unroll
  for (int s = 0; s < SQKV; s++) qp += ws[OFF_QKV + (s*NB + b)*4096 + hq*HDIM + o];
  int kvslot = g ? 3072 : 2048;
  #pragma unroll
  for (int s = 0; s < SQKV; s++) kp += ws[OFF_QKV + (s*NB + b)*4096 + kvslot + kv*HDIM + o];
  float qw_ = qnw[l*HDIM + o];
  float kw_ = knw[l*HDIM + o];
  float pos = (float)posids[b];
  __builtin_amdgcn_sched_barrier(0);

  // (b) KV prefetch: 8 positions per 32-lane group (static trip count)
  int grp = tid >> 5, q = tid & 31;
  int p0 = c*64;
  size_t pastb4 = ((((size_t)l*NB + b)*NHKV + kv)*NPAST)*(HDIM/4);
  size_t presbase = ((((size_t)l*NB + b)*NHKV + kv)*NPTOT)*HDIM;
  const float4* pk4 = (const float4*)pastK;
  const float4* pv4 = (const float4*)pastV;
  float4 kk[8], vv[8];
  #pragma unroll
  for (int i = 0; i < 8; i++) {
    size_t p = p0 + grp + i*8;
    kk[i] = pk4[pastb4 + p*(HDIM/4) + q];
    vv[i] = pv4[pastb4 + p*(HDIM/4) + q];
  }
  __builtin_amdgcn_sched_barrier(0);

  // (c) preamble compute: qknorm + rope (overlaps KV stream)
  float sq = wave_red_sum(qp*qp);
  float sk = wave_red_sum(kp*kp);
  if (lane == 0) { wr[w] = sq; wr[4+w] = sk; }
  __syncthreads();
  float qr = rsqrtf((wr[g<<1] + wr[(g<<1)+1])/HDIM + EPSF);
  float kr = rsqrtf((wr[4] + wr[5])/HDIM + EPSF);
  float qn = qp*qr*qw_;
  pre[g][o] = qn;
  if (g == 0) kpre[o] = kp*kr*kw_;
  else vf[o] = kp;
  __syncthreads();
  float ang = pos * expf(-(2.0f*(float)(o & 63)/(float)HDIM)*LOGTHETA);
  float sn, cs;
  sincosf(ang, &sn, &cs);
  {
    float rotq = (o < 64) ? -pre[g][o+64] : pre[g][o-64];
    qf[g][o] = qn*cs + rotq*sn;
    if (g == 0) {
      float kx = kpre[o];
      float rotk = (o < 64) ? -kpre[o+64] : kpre[o-64];
      kf[o] = kx*cs + rotk*sn;
    }
  }
  __syncthreads();

  // (d) scores + present-KV append (fire-and-forget stores; kk/vv already waited)
  float4 q0 = *(const float4*)&qf[0][q*4];
  float4 q1 = *(const float4*)&qf[1][q*4];
  float sc0[8], sc1[8];
  #pragma unroll
  for (int i = 0; i < 8; i++) {
    int p = p0 + grp + i*8;
    *(float4*)(out + PK_OFF + presbase + (size_t)p*HDIM + q*4) = kk[i];
    *(float4*)(out + PV_OFF + presbase + (size_t)p*HDIM + q*4) = vv[i];
    float d0 = q0.x*kk[i].x + q0.y*kk[i].y + q0.z*kk[i].z + q0.w*kk[i].w;
    float d1 = q1.x*kk[i].x + q1.y*kk[i].y + q1.z*kk[i].z + q1.w*kk[i].w;
    #pragma unroll
    for (int off = 16; off > 0; off >>= 1) {
      d0 += __shfl_xor(d0, off);
      d1 += __shfl_xor(d1, off);
    }
    sc0[i] = d0*QKSCALE; sc1[i] = d1*QKSCALE;
  }
  float xs0 = -1e30f, xs1 = -1e30f;
  float4 xv = make_float4(0.f, 0.f, 0.f, 0.f);
  if (c == SCH-1 && grp == 0) {
    float4 kX = *(const float4*)&kf[q*4];
    xv = *(const float4*)&vf[q*4];
    *(float4*)(out + PK_OFF + presbase + (size_t)NPAST*HDIM + q*4) = kX;
    *(float4*)(out + PV_OFF + presbase + (size_t)NPAST*HDIM + q*4) = xv;
    float d0 = q0.x*kX.x + q0.y*kX.y + q0.z*kX.z + q0.w*kX.w;
    float d1 = q1.x*kX.x + q1.y*kX.y + q1.z*kX.z + q1.w*kX.w;
    #pragma unroll
    for (int off = 16; off > 0; off >>= 1) {
      d0 += __shfl_xor(d0, off);
      d1 += __shfl_xor(d1, off);
    }
    xs0 = d0*QKSCALE; xs1 = d1*QKSCALE;
  }
  float m0 = sc0[0], m1 = sc1[0];
  #pragma unroll
  for (int i = 1; i < 8; i++) { m0 = fmaxf(m0, sc0[i]); m1 = fmaxf(m1, sc1[i]); }
  m0 = fmaxf(m0, xs0); m1 = fmaxf(m1, xs1);
  if (q == 0) { pm[grp][0] = m0; pm[grp][1] = m1; }
  __syncthreads();
  float M0 = -1e30f, M1 = -1e30f;
  #pragma unroll
  for (int j = 0; j < 8; j++) { M0 = fmaxf(M0, pm[j][0]); M1 = fmaxf(M1, pm[j][1]); }
  float l0 = 0.f, l1 = 0.f;
  float4 o0 = {0,0,0,0}, o1 = {0,0,0,0};
  #pragma unroll
  for (int j = 0; j < 8; j++) {
    float w0 = __expf(sc0[j] - M0), w1 = __expf(sc1[j] - M1);
    l0 += w0; l1 += w1;
    o0.x += w0*vv[j].x; o0.y += w0*vv[j].y; o0.z += w0*vv[j].z; o0.w += w0*vv[j].w;
    o1.x += w1*vv[j].x; o1.y += w1*vv[j].y; o1.z += w1*vv[j].z; o1.w += w1*vv[j].w;
  }
  { // new-token term: exp(-1e30 - M) == 0 folds it out elsewhere
    float w0 = __expf(xs0 - M0), w1 = __expf(xs1 - M1);
    l0 += w0; l1 += w1;
    o0.x += w0*xv.x; o0.y += w0*xv.y; o0.z += w0*xv.z; o0.w += w0*xv.w;
    o1.x += w1*xv.x; o1.y += w1*xv.y; o1.z += w1*xv.z; o1.w += w1*xv.w;
  }
  if (q == 0) { pl[grp][0] = l0; pl[grp][1] = l1; }
  *(float4*)&po[grp][0][q*4] = o0;
  *(float4*)&po[grp][1][q*4] = o1;
  __syncthreads();
  {
    int head = tid >> 7, dd = tid & 127;
    float acc = 0.f;
    #pragma unroll
    for (int j = 0; j < 8; j++) acc += po[j][head][dd];
    int base = ((b*NHKV + kv)*NG + head)*SCH + c;
    ws[OFF_AO + (size_t)base*HDIM + dd] = acc;
    if (dd == 0) {
      float ll = 0.f;
      #pragma unroll
      for (int j = 0; j < 8; j++) ll += pl[j][head];
      ws[OFF_AM + base] = (head ? M1 : M0);
      ws[OFF_AL + base] = ll;
    }
  }
}

// ---------------- K3: softmax combine + Wo GEMV partials (split=4) ------------
// grid (64 colTiles(16), 4 headQuads(512 rows)), 256 threads
__global__ __launch_bounds__(256) void k3_wo(const float* __restrict__ Wo_,
    float* __restrict__ ws, int l)
{
  int bx = blockIdx.x, by = blockIdx.y;
  int tid = threadIdx.x;
  __shared__ __align__(16) float x[NB][512];
  __shared__ float wf[NB][4][SCH];
  __shared__ float invL[NB][4];
  __shared__ __align__(16) float red[256*9];

  // (a) m/l finalize: 128 threads, one 16-lane group per (b,hh)
  if (tid < 128) {
    int b = tid >> 6, hh = (tid >> 4) & 3, cc = tid & 15;
    int hb = b*16 + by*4 + hh;
    float m  = ws[OFF_AM + hb*SCH + cc];
    float ll = ws[OFF_AL + hb*SCH + cc];
    float M = m;
    #pragma unroll
    for (int off = 8; off > 0; off >>= 1) M = fmaxf(M, __shfl_xor(M, off));
    float f = __expf(m - M);
    float Ls = ll*f;
    #pragma unroll
    for (int off = 8; off > 0; off >>= 1) Ls += __shfl_xor(Ls, off);
    wf[b][hh][cc] = f;
    if (cc == 0) invL[b][hh] = 1.0f/Ls;
  }
  __builtin_amdgcn_sched_barrier(0);

  // (b) weight stream
  int ct = tid & 3, rs = tid >> 2;      // 4 col-threads x 64 row-groups
  int col = bx*16 + ct*4;
  int r0 = rs*8;
  const float* Wp = Wo_ + (size_t)l*(NHQ*HDIM)*DIM + (size_t)(by*512 + r0)*DIM + col;
  float4 wb[8];
  #pragma unroll
  for (int i = 0; i < 8; i++) wb[i] = *(const float4*)(Wp + (size_t)i*DIM);
  __syncthreads();

  // (c) x combine (overlaps weight stream)
  for (int e = tid; e < 1024; e += 256) {
    int b = e >> 9, rr = e & 511, hh = rr >> 7, dd = rr & 127;
    int hb = b*16 + by*4 + hh;
    const float* op = ws + OFF_AO + (size_t)(hb*SCH)*HDIM + dd;
    float acc = 0.f;
    #pragma unroll
    for (int cc = 0; cc < SCH; cc++) acc += op[(size_t)cc*HDIM]*wf[b][hh][cc];
    x[b][rr] = acc*invL[b][hh];
  }
  __syncthreads();
  float a[2][4] = {};
  #pragma unroll
  for (int i = 0; i < 8; i++) {
    float x0 = x[0][r0+i], x1 = x[1][r0+i];
    a[0][0] += x0*wb[i].x; a[0][1] += x0*wb[i].y; a[0][2] += x0*wb[i].z; a[0][3] += x0*wb[i].w;
    a[1][0] += x1*wb[i].x; a[1][1] += x1*wb[i].y; a[1][2] += x1*wb[i].z; a[1][3] += x1*wb[i].w;
  }
  float* rp = red + tid*9;
  #pragma unroll
  for (int e = 0; e < 4; e++) { rp[e] = a[0][e]; rp[4+e] = a[1][e]; }
  __syncthreads();
  if (tid < 4) {
    float o[8] = {};
    #pragma unroll
    for (int j = 0; j < 64; j++) {
      const float* qq = red + (size_t)(j*4 + tid)*9;
      #pragma unroll
      for (int e = 0; e < 8; e++) o[e] += qq[e];
    }
    int cg = bx*16 + tid*4;
    #pragma unroll
    for (int e = 0; e < 4; e++) {
      ws[OFF_WO + (by*NB + 0)*DIM + cg + e] = o[e];
      ws[OFF_WO + (by*NB + 1)*DIM + cg + e] = o[4+e];
    }
  }
}

// ---------------- K4: h1+n2 recompute + Wg/Wu GEMV partials (split=4) ---------
// grid (96 colTiles(32), 4 rowSplits(256)), 256 threads
__global__ __launch_bounds__(256) void k4_mlp1(const float* __restrict__ Wg_,
    const float* __restrict__ Wu_, const float* __restrict__ ln2,
    float* __restrict__ ws, int l)
{
  int bx = blockIdx.x, by = blockIdx.y;
  int tid = threadIdx.x;
  int lane = tid & 63, w = tid >> 6;
  __shared__ __align__(16) float sh[NB][256];
  __shared__ __align__(16) float redG[256*9];
  __shared__ __align__(16) float redU[256*9];
  __shared__ float wr[8];

  // (a) preamble loads: h + WO partials (4 splits)
  int d = tid*4;
  float4 a0 = *(const float4*)(ws + OFF_H + d);
  float4 a1 = *(const float4*)(ws + OFF_H + DIM + d);
  #pragma unroll
  for (int s = 0; s < 4; s++) {
    float4 p0 = *(const float4*)(ws + OFF_WO + (s*NB + 0)*DIM + d);
    float4 p1 = *(const float4*)(ws + OFF_WO + (s*NB + 1)*DIM + d);
    a0.x += p0.x; a0.y += p0.y; a0.z += p0.z; a0.w += p0.w;
    a1.x += p1.x; a1.y += p1.y; a1.z += p1.z; a1.w += p1.w;
  }
  float4 lw = *(const float4*)(ln2 + (size_t)l*DIM + d);
  __builtin_amdgcn_sched_barrier(0);

  // (b) weight stream
  int ct = tid & 7, rs = tid >> 3;    // 8 col-threads x 32 row-groups
  int col = bx*32 + ct*4;
  int r0 = rs*8;
  const float* Wgp = Wg_ + (size_t)l*DIM*NFF + (size_t)(by*256 + r0)*NFF + col;
  const float* Wup = Wu_ + (size_t)l*DIM*NFF + (size_t)(by*256 + r0)*NFF + col;
  float4 wg[8], wu[8];
  #pragma unroll
  for (int i = 0; i < 8; i++) {
    wg[i] = *(const float4*)(Wgp + (size_t)i*NFF);
    wu[i] = *(const float4*)(Wup + (size_t)i*NFF);
  }

  // (c) preamble compute
  if (bx == 0 && by == 0) {
    *(float4*)(ws + OFF_H1 + d) = a0;
    *(float4*)(ws + OFF_H1 + DIM + d) = a1;
  }
  float s0 = wave_red_sum(a0.x*a0.x + a0.y*a0.y + a0.z*a0.z + a0.w*a0.w);
  float s1 = wave_red_sum(a1.x*a1.x + a1.y*a1.y + a1.z*a1.z + a1.w*a1.w);
  if (lane == 0) { wr[w] = s0; wr[4+w] = s1; }
  __syncthreads();
  float rq0 = rsqrtf((wr[0]+wr[1]+wr[2]+wr[3])/DIM + EPSF);
  float rq1 = rsqrtf((wr[4]+wr[5]+wr[6]+wr[7])/DIM + EPSF);
  int r = d - by*256;
  if (r >= 0 && r < 256) {
    sh[0][r] = a0.x*rq0*lw.x; sh[0][r+1] = a0.y*rq0*lw.y;
    sh[0][r+2] = a0.z*rq0*lw.z; sh[0][r+3] = a0.w*rq0*lw.w;
    sh[1][r] = a1.x*rq1*lw.x; sh[1][r+1] = a1.y*rq1*lw.y;
    sh[1][r+2] = a1.z*rq1*lw.z; sh[1][r+3] = a1.w*rq1*lw.w;
  }
  __syncthreads();

  float ag[2][4] = {}, au[2][4] = {};
  #pragma unroll
  for (int i = 0; i < 8; i++) {
    float x0 = sh[0][r0+i], x1 = sh[1][r0+i];
    ag[0][0] += x0*wg[i].x; ag[0][1] += x0*wg[i].y; ag[0][2] += x0*wg[i].z; ag[0][3] += x0*wg[i].w;
    ag[1][0] += x1*wg[i].x; ag[1][1] += x1*wg[i].y; ag[1][2] += x1*wg[i].z; ag[1][3] += x1*wg[i].w;
    au[0][0] += x0*wu[i].x; au[0][1] += x0*wu[i].y; au[0][2] += x0*wu[i].z; au[0][3] += x0*wu[i].w;
    au[1][0] += x1*wu[i].x; au[1][1] += x1*wu[i].y; au[1][2] += x1*wu[i].z; au[1][3] += x1*wu[i].w;
  }
  float* rpG = redG + tid*9;
  float* rpU = redU + tid*9;
  #pragma unroll
  for (int e = 0; e < 4; e++) {
    rpG[e] = ag[0][e]; rpG[4+e] = ag[1][e];
    rpU[e] = au[0][e]; rpU[4+e] = au[1][e];
  }
  __syncthreads();
  if (tid < 8) {              // wave 0 reduces G
    float o[8] = {};
    #pragma unroll
    for (int j = 0; j < 32; j++) {
      const float* qq = redG + (size_t)(j*8 + tid)*9;
      #pragma unroll
      for (int e = 0; e < 8; e++) o[e] += qq[e];
    }
    int cg = bx*32 + tid*4;
    #pragma unroll
    for (int e = 0; e < 4; e++) {
      ws[OFF_G + (by*NB + 0)*NFF + cg + e] = o[e];
      ws[OFF_G + (by*NB + 1)*NFF + cg + e] = o[4+e];
    }
  } else if (tid >= 64 && tid < 72) {   // wave 1 reduces U concurrently
    int t = tid - 64;
    float o[8] = {};
    #pragma unroll
    for (int j = 0; j < 32; j++) {
      const float* qq = redU + (size_t)(j*8 + t)*9;
      #pragma unroll
      for (int e = 0; e < 8; e++) o[e] += qq[e];
    }
    int cg = bx*32 + t*4;
    #pragma unroll
    for (int e = 0; e < 4; e++) {
      ws[OFF_U + (by*NB + 0)*NFF + cg + e] = o[e];
      ws[OFF_U + (by*NB + 1)*NFF + cg + e] = o[4+e];
    }
  }
}

// ---------------- K5: swiglu slice + Wd GEMV partials -------------------------
// grid (32 colTiles(32), 8 ffSplits(384)), 256 threads
__global__ __launch_bounds__(256) void k5_mlp2(const float* __restrict__ Wd_,
    float* __restrict__ ws, int l)
{
  int bx = blockIdx.x, by = blockIdx.y;
  int tid = threadIdx.x;
  __shared__ __align__(16) float act[NB][384];
  __shared__ __align__(16) float red[256*9];

  // (a) preamble loads: G/U partials (4 splits), 192 active threads
  float4 gacc = {0,0,0,0}, uacc = {0,0,0,0};
  int pb = 0, pf4 = 0;
  if (tid < 192) {
    pb = tid / 96; pf4 = tid % 96;
    int f4 = (by*384)/4 + pf4;
    const float4* Gp = (const float4*)(ws + OFF_G);
    const float4* Up = (const float4*)(ws + OFF_U);
    #pragma unroll
    for (int s = 0; s < 4; s++) {
      float4 g4 = Gp[(size_t)(s*NB + pb)*(NFF/4) + f4];
      float4 u4 = Up[(size_t)(s*NB + pb)*(NFF/4) + f4];
      gacc.x += g4.x; gacc.y += g4.y; gacc.z += g4.z; gacc.w += g4.w;
      uacc.x += u4.x; uacc.y += u4.y; uacc.z += u4.z; uacc.w += u4.w;
    }
  }
  __builtin_amdgcn_sched_barrier(0);

  // (b) weight stream
  int ct = tid & 7, rs = tid >> 3;
  int col = bx*32 + ct*4;
  int r0 = rs*12;
  const float* Wp = Wd_ + (size_t)l*NFF*DIM + (size_t)(by*384 + r0)*DIM + col;
  float4 wb[12];
  #pragma unroll
  for (int i = 0; i < 12; i++) wb[i] = *(const float4*)(Wp + (size_t)i*DIM);

  // (c) swiglu + LDS store
  if (tid < 192) {
    float4 r;
    r.x = (gacc.x / (1.0f + __expf(-gacc.x)))*uacc.x;
    r.y = (gacc.y / (1.0f + __expf(-gacc.y)))*uacc.y;
    r.z = (gacc.z / (1.0f + __expf(-gacc.z)))*uacc.z;
    r.w = (gacc.w / (1.0f + __expf(-gacc.w)))*uacc.w;
    *(float4*)&act[pb][pf4*4] = r;
  }
  __syncthreads();

  float a[2][4] = {};
  #pragma unroll
  for (int i = 0; i < 12; i++) {
    float x0 = act[0][r0+i], x1 = act[1][r0+i];
    a[0][0] += x0*wb[i].x; a[0][1] += x0*wb[i].y; a[0][2] += x0*wb[i].z; a[0][3] += x0*wb[i].w;
    a[1][0] += x1*wb[i].x; a[1][1] += x1*wb[i].y; a[1][2] += x1*wb[i].z; a[1][3] += x1*wb[i].w;
  }
  float* rp = red + tid*9;
  #pragma unroll
  for (int e = 0; e < 4; e++) { rp[e] = a[0][e]; rp[4+e] = a[1][e]; }
  __syncthreads();
  if (tid < 8) {
    float o[8] = {};
    #pragma unroll
    for (int j = 0; j < 32; j++) {
      const float* qq = red + (size_t)(j*8 + tid)*9;
      #pragma unroll
      for (int e = 0; e < 8; e++) o[e] += qq[e];
    }
    int cg = bx*32 + tid*4;
    #pragma unroll
    for (int e = 0; e < 4; e++) {
      ws[OFF_WD + (by*NB + 0)*DIM + cg + e] = o[e];
      ws[OFF_WD + (by*NB + 1)*DIM + cg + e] = o[4+e];
    }
  }
}

// ---------------- KF: finalize h2 + final rmsnorm -> nf (1 block) -------------
__global__ __launch_bounds__(256) void kf_final(const float* __restrict__ fnw,
    float* __restrict__ ws)
{
  int tid = threadIdx.x;
  int lane = tid & 63, w = tid >> 6;
  __shared__ float wr[8];
  int d = tid*4;
  float4 a0 = *(const float4*)(ws + OFF_H1 + d);
  float4 a1 = *(const float4*)(ws + OFF_H1 + DIM + d);
  #pragma unroll
  for (int s = 0; s < 8; s++) {
    float4 p0 = *(const float4*)(ws + OFF_WD + (s*NB + 0)*DIM + d);
    float4 p1 = *(const float4*)(ws + OFF_WD + (s*NB + 1)*DIM + d);
    a0.x += p0.x; a0.y += p0.y; a0.z += p0.z; a0.w += p0.w;
    a1.x += p1.x; a1.y += p1.y; a1.z += p1.z; a1.w += p1.w;
  }
  float4 fw = *(const float4*)(fnw + d);
  float s0 = wave_red_sum(a0.x*a0.x + a0.y*a0.y + a0.z*a0.z + a0.w*a0.w);
  float s1 = wave_red_sum(a1.x*a1.x + a1.y*a1.y + a1.z*a1.z + a1.w*a1.w);
  if (lane == 0) { wr[w] = s0; wr[4+w] = s1; }
  __syncthreads();
  float rq0 = rsqrtf((wr[0]+wr[1]+wr[2]+wr[3])/DIM + EPSF);
  float rq1 = rsqrtf((wr[4]+wr[5]+wr[6]+wr[7])/DIM + EPSF);
  float4 n0 = make_float4(a0.x*rq0*fw.x, a0.y*rq0*fw.y, a0.z*rq0*fw.z, a0.w*rq0*fw.w);
  float4 n1 = make_float4(a1.x*rq1*fw.x, a1.y*rq1*fw.y, a1.z*rq1*fw.z, a1.w*rq1*fw.w);
  *(float4*)(ws + OFF_N1 + d) = n0;
  *(float4*)(ws + OFF_N1 + DIM + d) = n1;
}

// ---------------- K6: lm_head GEMV (nf precomputed) ---------------------------
// grid 2374 blocks (64 cols each), 256 threads
__global__ __launch_bounds__(256) void k6_lmhead(const float* __restrict__ lmw,
    const float* __restrict__ ws, float* __restrict__ out)
{
  __shared__ __align__(16) float nf[NB*DIM];
  __shared__ __align__(16) float red[256*9];
  int tid = threadIdx.x;
  *(float4*)&nf[tid*4]        = *(const float4*)(ws + OFF_N1 + tid*4);
  *(float4*)&nf[1024 + tid*4] = *(const float4*)(ws + OFF_N1 + 1024 + tid*4);
  __syncthreads();

  int ct = tid & 15, rs = tid >> 4;
  int col = blockIdx.x*64 + ct*4;
  const float* Wp = lmw + (size_t)(rs*64)*NVOCAB + col;
  float a[2][4] = {};
  for (int t = 0; t < 8; t++) {
    float4 wb[8];
    #pragma unroll
    for (int i = 0; i < 8; i++)
      wb[i] = *(const float4*)(Wp + (size_t)(t*8 + i)*NVOCAB);
    #pragma unroll
    for (int i = 0; i < 8; i++) {
      int rr = rs*64 + t*8 + i;
      float x0 = nf[rr], x1 = nf[DIM+rr];
      a[0][0] += x0*wb[i].x; a[0][1] += x0*wb[i].y; a[0][2] += x0*wb[i].z; a[0][3] += x0*wb[i].w;
      a[1][0] += x1*wb[i].x; a[1][1] += x1*wb[i].y; a[1][2] += x1*wb[i].z; a[1][3] += x1*wb[i].w;
    }
  }
  float* rp = red + tid*9;
  #pragma unroll
  for (int e = 0; e < 4; e++) { rp[e] = a[0][e]; rp[4+e] = a[1][e]; }
  __syncthreads();
  if (tid < 16) {
    float o[8] = {};
    #pragma unroll
    for (int j = 0; j < 16; j++) {
      const float* qq = red + (size_t)(j*16 + tid)*9;
      #pragma unroll
      for (int e = 0; e < 8; e++) o[e] += qq[e];
    }
    int cg = blockIdx.x*64 + tid*4;
    #pragma unroll
    for (int e = 0; e < 4; e++) {
      out[cg + e] = o[e];
      out[NVOCAB + cg + e] = o[4+e];
    }
  }
}

extern "C" void kernel_launch(void* const* d_in, const int* in_sizes, int n_in,
                              void* d_out, int out_size, void* d_ws, size_t ws_size,
                              hipStream_t stream) {
  (void)in_sizes; (void)n_in; (void)out_size; (void)ws_size;
  const float* embeds = (const float*)d_in[0];
  const int*   posids = (const int*)d_in[1];
  const float* pastK  = (const float*)d_in[2];
  const float* pastV  = (const float*)d_in[3];
  const float* Wq     = (const float*)d_in[4];
  const float* Wk     = (const float*)d_in[5];
  const float* Wv     = (const float*)d_in[6];
  const float* Wo     = (const float*)d_in[7];
  const float* Wg     = (const float*)d_in[8];
  const float* Wu     = (const float*)d_in[9];
  const float* Wd     = (const float*)d_in[10];
  const float* ln1    = (const float*)d_in[11];
  const float* ln2    = (const float*)d_in[12];
  const float* qnw    = (const float*)d_in[13];
  const float* knw    = (const float*)d_in[14];
  const float* fnw    = (const float*)d_in[15];
  const float* lmw    = (const float*)d_in[16];
  float* out = (float*)d_out;
  float* ws  = (float*)d_ws;

  for (int l = 0; l < NL; l++) {
    k1_qkv <<<256, 256, 0, stream>>>(embeds, Wq, Wk, Wv, ln1, ws, l);
    k2_attn<<<dim3(SCH, NHKV, NB), 256, 0, stream>>>(pastK, pastV, posids, qnw, knw, out, ws, l);
    k3_wo  <<<dim3(64, 4), 256, 0, stream>>>(Wo, ws, l);
    k4_mlp1<<<dim3(96, 4), 256, 0, stream>>>(Wg, Wu, ln2, ws, l);
    k5_mlp2<<<dim3(32, 8), 256, 0, stream>>>(Wd, ws, l);
  }
  kf_final<<<1, 256, 0, stream>>>(fnw, ws);
  k6_lmhead<<<NVOCAB/64, 256, 0, stream>>>(lmw, ws, out);
}